// Round 3
// baseline (3751.081 us; speedup 1.0000x reference)
//
#include <hip/hip_runtime.h>
#include <math.h>

#define HD 128  // hidden dim

// ---------------------------------------------------------------- GEMM
// C[M,N] (+)= A[M,K] @ W[K,N] (+bias), act: 0 none, 1 lrelu, 2 sigmoid
// 256 threads, 128x128 tile, each thread 4 rows x 16 cols, BK=32.
#define BM 128
#define BK 32

__global__ __launch_bounds__(256)
void gemm_kernel(const float* __restrict__ A, const float* __restrict__ W,
                 const float* __restrict__ bias, float* __restrict__ C,
                 int M, int K, int N, int acc, int act)
{
    __shared__ float sA[BM][BK + 1];   // +1 pad: conflict-free per-row reads
    __shared__ float sW[BK][128];

    const int tid = threadIdx.x;
    const int r0 = (tid >> 3) * 4;     // 0..124
    const int c0 = (tid & 7) * 16;     // 0..112
    const int mBase = blockIdx.x * BM;
    const int nBase = blockIdx.y * 128;
    const bool k4 = (K & 3) == 0;

    float accv[4][16];
#pragma unroll
    for (int i = 0; i < 4; ++i)
#pragma unroll
        for (int j = 0; j < 16; ++j) accv[i][j] = 0.f;

    const int kTiles = (K + BK - 1) / BK;
    for (int kt = 0; kt < kTiles; ++kt) {
        const int k0 = kt * BK;
        // ---- stage A tile [BM][BK]
#pragma unroll
        for (int p = 0; p < 4; ++p) {
            int row = p * 32 + (tid >> 3);
            int kq  = (tid & 7) * 4;
            int gr  = mBase + row;
            float v0 = 0.f, v1 = 0.f, v2 = 0.f, v3 = 0.f;
            if (gr < M) {
                const float* ap = A + (size_t)gr * K + k0 + kq;
                if (k4 && k0 + kq + 3 < K) {
                    float4 v = *(const float4*)ap;
                    v0 = v.x; v1 = v.y; v2 = v.z; v3 = v.w;
                } else {
                    if (k0 + kq + 0 < K) v0 = ap[0];
                    if (k0 + kq + 1 < K) v1 = ap[1];
                    if (k0 + kq + 2 < K) v2 = ap[2];
                    if (k0 + kq + 3 < K) v3 = ap[3];
                }
            }
            sA[row][kq + 0] = v0; sA[row][kq + 1] = v1;
            sA[row][kq + 2] = v2; sA[row][kq + 3] = v3;
        }
        // ---- stage W tile [BK][128]
#pragma unroll
        for (int p = 0; p < 4; ++p) {
            int lin = p * 1024 + tid * 4;
            int kr = lin >> 7, nc = lin & 127;
            float4 v = make_float4(0.f, 0.f, 0.f, 0.f);
            if (k0 + kr < K) v = *(const float4*)(W + (size_t)(k0 + kr) * N + nBase + nc);
            *(float4*)&sW[kr][nc] = v;
        }
        __syncthreads();
#pragma unroll 4
        for (int k = 0; k < BK; ++k) {
            float a0 = sA[r0 + 0][k], a1 = sA[r0 + 1][k];
            float a2 = sA[r0 + 2][k], a3 = sA[r0 + 3][k];
            float wv[16];
            *(float4*)&wv[0]  = *(const float4*)&sW[k][c0 + 0];
            *(float4*)&wv[4]  = *(const float4*)&sW[k][c0 + 4];
            *(float4*)&wv[8]  = *(const float4*)&sW[k][c0 + 8];
            *(float4*)&wv[12] = *(const float4*)&sW[k][c0 + 12];
#pragma unroll
            for (int j = 0; j < 16; ++j) {
                accv[0][j] += a0 * wv[j];
                accv[1][j] += a1 * wv[j];
                accv[2][j] += a2 * wv[j];
                accv[3][j] += a3 * wv[j];
            }
        }
        __syncthreads();
    }

    float bb[16];
    if (bias) {
#pragma unroll
        for (int q = 0; q < 4; ++q)
            *(float4*)&bb[q * 4] = *(const float4*)(bias + nBase + c0 + q * 4);
    } else {
#pragma unroll
        for (int j = 0; j < 16; ++j) bb[j] = 0.f;
    }
#pragma unroll
    for (int i = 0; i < 4; ++i) {
        int gr = mBase + r0 + i;
        if (gr >= M) continue;
        float* cp = C + (size_t)gr * N + nBase + c0;
#pragma unroll
        for (int q = 0; q < 4; ++q) {
            float4 old;
            if (acc) old = *(const float4*)(cp + q * 4);
            float o[4];
#pragma unroll
            for (int u = 0; u < 4; ++u) {
                float v = accv[i][q * 4 + u] + bb[q * 4 + u];
                if (acc) v += ((const float*)&old)[u];
                if (act == 1) v = v > 0.f ? v : 0.1f * v;
                else if (act == 2) v = 1.f / (1.f + expf(-v));
                o[u] = v;
            }
            *(float4*)(cp + q * 4) = make_float4(o[0], o[1], o[2], o[3]);
        }
    }
}

// ---------------------------------------------------------------- CSR build
__global__ void hist_k(int* __restrict__ cnt, const int* __restrict__ dst, int E)
{
    int i = blockIdx.x * 256 + threadIdx.x;
    if (i < E) atomicAdd(&cnt[dst[i]], 1);
}

// single block 256 threads: rowptr[0..n] = exclusive scan of cnt[0..n-1]
__global__ void scan_k(int* __restrict__ rowptr, const int* __restrict__ cnt, int n)
{
    __shared__ int part[257];
    int t = threadIdx.x;
    int chunk = (n + 255) / 256;
    int lo = t * chunk; if (lo > n) lo = n;
    int hi = lo + chunk; if (hi > n) hi = n;
    int s = 0;
    for (int i = lo; i < hi; ++i) s += cnt[i];
    part[t + 1] = s;
    if (t == 0) part[0] = 0;
    __syncthreads();
    if (t == 0) for (int i = 1; i <= 256; ++i) part[i] += part[i - 1];
    __syncthreads();
    int run = part[t];
    for (int i = lo; i < hi; ++i) { rowptr[i] = run; run += cnt[i]; }
    if (t == 0) rowptr[n] = part[256];
}

__global__ void fill_k(int* __restrict__ eidx, int* __restrict__ cursor,
                       const int* __restrict__ dst, int E)
{
    int i = blockIdx.x * 256 + threadIdx.x;
    if (i < E) eidx[atomicAdd(&cursor[dst[i]], 1)] = i;
}

// ---------------------------------------------------------------- CSR gather
// One wave (64 lanes) per destination row; lane covers 2 feats (float2).
// out[d*ostride+ooff+:] = act( bias + sum_e w_e * X[src[e]][:] )
// mode 0: w=1   1: w=wattr[e]   2: w=1/deg   3: w=softmax(6-wattr)[e]
__global__ __launch_bounds__(256)
void seg_gather(float* __restrict__ out, const float* __restrict__ X,
                const int* __restrict__ rowptr, const int* __restrict__ eidx,
                const int* __restrict__ src, const float* __restrict__ wattr,
                const float* __restrict__ bias, int n, int ostride, int ooff,
                int act, int mode)
{
    int d = blockIdx.x * 4 + (threadIdx.x >> 6);
    if (d >= n) return;
    int lane = threadIdx.x & 63;
    int lo = rowptr[d], hi = rowptr[d + 1];
    float w0 = 1.f, mx = 0.f, iden = 0.f;
    if (mode == 2) w0 = (hi > lo) ? 1.f / (float)(hi - lo) : 0.f;
    if (mode == 3) {
        mx = -1e30f;
        for (int i = lo; i < hi; ++i) mx = fmaxf(mx, 6.f - wattr[eidx[i]]);
        float den = 0.f;
        for (int i = lo; i < hi; ++i) den += expf(6.f - wattr[eidx[i]] - mx);
        iden = 1.f / den;
    }
    float ax = 0.f, ay = 0.f;
    for (int i = lo; i < hi; ++i) {
        int e = eidx[i];
        int s = src ? src[e] : e;
        float w;
        if (mode == 0) w = 1.f;
        else if (mode == 1) w = wattr[e];
        else if (mode == 2) w = w0;
        else w = expf(6.f - wattr[e] - mx) * iden;
        float2 v = *(const float2*)(X + (size_t)s * HD + 2 * lane);
        ax += w * v.x; ay += w * v.y;
    }
    if (bias) { float2 b = *(const float2*)(bias + 2 * lane); ax += b.x; ay += b.y; }
    if (act == 1) { ax = ax > 0.f ? ax : 0.1f * ax; ay = ay > 0.f ? ay : 0.1f * ay; }
    *(float2*)(out + (size_t)d * ostride + ooff + 2 * lane) = make_float2(ax, ay);
}

// ---------------------------------------------------------------- misc kernels
__global__ void gather128(float* __restrict__ out, const float* __restrict__ in,
                          const int* __restrict__ idx, int n)
{
    long i = (long)blockIdx.x * 256 + threadIdx.x;
    if (i >= (long)n * HD) return;
    int r = (int)(i >> 7), f = (int)(i & 127);
    out[i] = in[(size_t)idx[r] * HD + f];
}

// in-place: z -> z*h + (1-z)*t
__global__ void combine_gate(float* __restrict__ zx, const float* __restrict__ h,
                             const float* __restrict__ t, long n)
{
    long i = (long)blockIdx.x * 256 + threadIdx.x;
    if (i >= n) return;
    float z = zx[i];
    zx[i] = z * h[i] + (1.f - z) * t[i];
}

// torch GRUCell gate math; h [M,128] in place, gi/gh [M,384] (bias already added)
__global__ void gru_gate(float* __restrict__ h, const float* __restrict__ gi,
                         const float* __restrict__ gh, int M)
{
    long i = (long)blockIdx.x * 256 + threadIdx.x;
    if (i >= (long)M * HD) return;
    int row = (int)(i >> 7), f = (int)(i & 127);
    size_t o = (size_t)row * 384 + f;
    float r = 1.f / (1.f + expf(-(gi[o] + gh[o])));
    float z = 1.f / (1.f + expf(-(gi[o + 128] + gh[o + 128])));
    float n = tanhf(gi[o + 256] + r * gh[o + 256]);
    h[i] = (1.f - z) * n + z * h[i];
}

__global__ void transpose_k(float* __restrict__ out, const float* __restrict__ in, int R, int C)
{
    long i = (long)blockIdx.x * 256 + threadIdx.x;
    if (i >= (long)R * C) return;
    int r = (int)(i / C), c = (int)(i % C);
    out[(size_t)c * R + r] = in[i];
}

__global__ void dot_score(float* __restrict__ sc, const float* __restrict__ kb,
                          const float* __restrict__ qs, const int* __restrict__ batch, int n)
{
    int v = blockIdx.x * 256 + threadIdx.x;
    if (v >= n) return;
    const float4* a = (const float4*)(kb + (size_t)v * HD);
    const float4* q = (const float4*)(qs + (size_t)batch[v] * HD);
    float acc = 0.f;
#pragma unroll
    for (int i = 0; i < 32; ++i) {
        float4 x = a[i], y = q[i];
        acc += x.x * y.x + x.y * y.y + x.z * y.z + x.w * y.w;
    }
    sc[v] = acc * 0.08838834764831843f;  // 1/sqrt(128)
}

// order-preserving float<->uint for atomicMax (memset-0 init == -inf)
__device__ __forceinline__ unsigned enc_f(float f) {
    unsigned u = __float_as_uint(f);
    return (u & 0x80000000u) ? ~u : (u | 0x80000000u);
}
__device__ __forceinline__ float dec_f(unsigned u) {
    return (u & 0x80000000u) ? __uint_as_float(u & 0x7fffffffu) : __uint_as_float(~u);
}

__global__ void seg_max_k(unsigned* __restrict__ m, const float* __restrict__ s,
                          const int* __restrict__ seg, int n)
{
    int i = blockIdx.x * 256 + threadIdx.x;
    if (i < n) atomicMax(&m[seg[i]], enc_f(s[i]));
}
__global__ void seg_expsum_k(float* __restrict__ ev, float* __restrict__ d,
                             const unsigned* __restrict__ m, const float* __restrict__ s,
                             const int* __restrict__ seg, int n)
{
    int i = blockIdx.x * 256 + threadIdx.x;
    if (i >= n) return;
    float e = expf(s[i] - dec_f(m[seg[i]]));
    ev[i] = e;
    atomicAdd(&d[seg[i]], e);
}
__global__ void seg_norm_k(float* __restrict__ wv, const float* __restrict__ d,
                           const int* __restrict__ seg, int n)
{
    int i = blockIdx.x * 256 + threadIdx.x;
    if (i < n) wv[i] /= d[seg[i]];
}

__global__ void pdist_k(float* __restrict__ out, const float* __restrict__ A,
                        const float* __restrict__ Bm, const int* __restrict__ ia,
                        const int* __restrict__ ib, int P)
{
    int p = blockIdx.x * 256 + threadIdx.x;
    if (p >= P) return;
    const float4* a = (const float4*)(A + (size_t)ia[p] * HD);
    const float4* b = (const float4*)(Bm + (size_t)ib[p] * HD);
    float acc = 0.f;
#pragma unroll
    for (int i = 0; i < 32; ++i) {
        float4 x = a[i], y = b[i];
        float d0 = x.x - y.x + 1e-6f, d1 = x.y - y.y + 1e-6f;
        float d2 = x.z - y.z + 1e-6f, d3 = x.w - y.w + 1e-6f;
        acc += d0 * d0 + d1 * d1 + d2 * d2 + d3 * d3;
    }
    out[p] = sqrtf(acc);
}

// ---------------------------------------------------------------- host

static inline unsigned gupd(size_t n) { return (unsigned)((n + 255) / 256); }
static inline unsigned gup4(size_t n) { return (unsigned)((n + 3) / 4); }

static void gemm(hipStream_t st, const float* A, const float* W, const float* bias,
                 float* C, int M, int K, int N, int acc, int act)
{
    dim3 g((M + BM - 1) / BM, N / 128);
    hipLaunchKernelGGL(gemm_kernel, g, dim3(256), 0, st, A, W, bias, C, M, K, N, acc, act);
}

extern "C" void kernel_launch(void* const* d_in, const int* in_sizes, int n_in,
                              void* d_out, int out_size, void* d_ws, size_t ws_size,
                              hipStream_t stream)
{
    (void)n_in; (void)out_size;
    const float* vert_x  = (const float*)d_in[0];
    const float* site_x  = (const float*)d_in[1];
    const float* masf_x  = (const float*)d_in[2];
    const float* prot_ea = (const float*)d_in[3];
    const float* prom_ea = (const float*)d_in[4];
    const int* vert_src = (const int*)d_in[5];
    const int* vert_dst = (const int*)d_in[6];
    const int* vbatch   = (const int*)d_in[7];
    const int* comp_src = (const int*)d_in[8];
    const int* comp_dst = (const int*)d_in[9];
    const int* site_src = (const int*)d_in[10];
    const int* site_dst = (const int*)d_in[11];
    const int* masf_src = (const int*)d_in[12];
    const int* masf_dst = (const int*)d_in[13];
    const int* prot_src = (const int*)d_in[14];
    const int* prot_dst = (const int*)d_in[15];
    const int* prom_src = (const int*)d_in[16];
    const int* prom_dst = (const int*)d_in[17];
    const int* anch_src = (const int*)d_in[18];
    const int* anch_dst = (const int*)d_in[19];
    const int* ag_a = (const int*)d_in[20];
    const int* ag_g = (const int*)d_in[21];
    const int* aa0  = (const int*)d_in[22];
    const int* aa1  = (const int*)d_in[23];
    const int* gg0  = (const int*)d_in[24];
    const int* gg1  = (const int*)d_in[25];
    const float* W_emb = (const float*)d_in[26];
    const float* b_emb = (const float*)d_in[27];
    const float* gW_main = (const float*)d_in[28];
    const float* gW_s2m  = (const float*)d_in[29];
    const float* gW_gm   = (const float*)d_in[30];
    const float* gb_gm   = (const float*)d_in[31];
    const float* gW_q    = (const float*)d_in[32];
    const float* gW_k    = (const float*)d_in[33];
    const float* gW_mrg  = (const float*)d_in[34];
    const float* gW_gs   = (const float*)d_in[35];
    const float* gb_gs   = (const float*)d_in[36];
    const float* gm_Wih = (const float*)d_in[37];
    const float* gm_Whh = (const float*)d_in[38];
    const float* gm_bih = (const float*)d_in[39];
    const float* gm_bhh = (const float*)d_in[40];
    const float* gs_Wih = (const float*)d_in[41];
    const float* gs_Whh = (const float*)d_in[42];
    const float* gs_bih = (const float*)d_in[43];
    const float* gs_bhh = (const float*)d_in[44];
    const float* W_s0 = (const float*)d_in[45];
    const float* b_s0 = (const float*)d_in[46];
    const float* W_s1 = (const float*)d_in[47];
    const float* b_s1 = (const float*)d_in[48];
    const float* W_so = (const float*)d_in[49];
    const float* b_so = (const float*)d_in[50];
    const float* W_m0 = (const float*)d_in[51];
    const float* b_m0 = (const float*)d_in[52];
    const float* W_m1 = (const float*)d_in[53];
    const float* b_m1 = (const float*)d_in[54];
    const float* W_mo = (const float*)d_in[55];
    const float* b_mo = (const float*)d_in[56];
    const float* W_a0 = (const float*)d_in[57];
    const float* b_a0 = (const float*)d_in[58];
    const float* W_a1 = (const float*)d_in[59];
    const float* b_a1 = (const float*)d_in[60];
    const float* W_ao = (const float*)d_in[61];
    const float* b_ao = (const float*)d_in[62];
    const float* W_ds = (const float*)d_in[63];
    const float* b_ds = (const float*)d_in[64];
    const float* W_dc = (const float*)d_in[65];
    const float* b_dc = (const float*)d_in[66];

    const int B = 256, NG = 4000, NA = 10000, Ns = 80000, Nm = 80000;
    const int Nv = in_sizes[7];
    const int FV = in_sizes[0] / Nv;
    const int Fs = in_sizes[1] / Ns;
    const int Fm = in_sizes[2] / Nm;
    const int Ev = in_sizes[5], Ec = in_sizes[8], Es = in_sizes[10], Em = in_sizes[12];
    const int Ep = in_sizes[14], Ea = in_sizes[18];
    const int Pag = in_sizes[20], Paa = in_sizes[22], Pgg = in_sizes[24];
    const int D = in_sizes[28] / (HD * HD);

    // ---- workspace layout (floats) --------------------------------------
    float* ws = (float*)d_ws;
    size_t off = 0;
    auto take = [&](size_t n) { size_t o = off; off += n; return o; };
    float* vert  = ws + take((size_t)Nv * HD);
    float* supe  = ws + take((size_t)B * HD);
    float* qsup  = ws + take((size_t)B * HD);
    float* pool  = ws + take((size_t)B * HD);
    float* msup  = ws + take((size_t)B * HD);
    float* zsup  = ws + take((size_t)B * HD);
    float* gis   = ws + take((size_t)B * 3 * HD);
    float* ghs   = ws + take((size_t)B * 3 * HD);
    float* tsml  = ws + take((size_t)B * HD);
    float* grp   = ws + take((size_t)NG * HD);
    float* site_o = ws + take((size_t)Ns * HD);
    float* masf_o = ws + take((size_t)Nm * HD);
    float* anch  = ws + take((size_t)NA * 2 * HD);
    float* ah1   = ws + take((size_t)NA * HD);
    float* ah2   = ws + take((size_t)NA * HD);
    float* axw   = ws + take((size_t)NA * HD);
    float* aout  = ws + take((size_t)NA * HD);
    float* pa    = ws + take((size_t)NA * HD);
    float* pg    = ws + take((size_t)NG * HD);
    float* score = ws + take((size_t)Nv);
    unsigned* segm = (unsigned*)(ws + take((size_t)B));
    float* segd  = ws + take((size_t)B);
    float* WTm_ih = ws + take((size_t)3 * HD * HD);
    float* WTm_hh = ws + take((size_t)3 * HD * HD);
    float* WTs_ih = ws + take((size_t)3 * HD * HD);
    float* WTs_hh = ws + take((size_t)3 * HD * HD);
    const size_t NvH = (size_t)Nv * HD, NsH = (size_t)Ns * HD;
    float* T = ws + take(3 * NsH);   // shared temp region

    // ---- CSR arrays (ints) ----------------------------------------------
    int* ib = (int*)(ws + off);
    size_t ioff = 0;
    auto taki = [&](size_t n) { size_t o = ioff; ioff += n; return o; };
    int* cnt    = ib + taki((size_t)Ns + 1);
    int* cursor = ib + taki((size_t)Ns + 1);
    int* rp_v = ib + taki((size_t)Nv + 1);  int* ei_v = ib + taki((size_t)Ev);
    int* rp_c = ib + taki((size_t)NG + 1);  int* ei_c = ib + taki((size_t)Ec);
    int* rp_s = ib + taki((size_t)Ns + 1);  int* ei_s = ib + taki((size_t)Es);
    int* rp_m = ib + taki((size_t)Nm + 1);  int* ei_m = ib + taki((size_t)Em);
    int* rp_p = ib + taki((size_t)NA + 1);  int* ei_p = ib + taki((size_t)Ep);
    int* rp_q = ib + taki((size_t)NA + 1);  int* ei_q = ib + taki((size_t)Ep);
    int* rp_a = ib + taki((size_t)NA + 1);  int* ei_a = ib + taki((size_t)Ea);
    int* rp_b = ib + taki((size_t)B + 1);   int* ei_b = ib + taki((size_t)Nv);
    if (ws_size < off * sizeof(float) + ioff * sizeof(int)) return;

    auto build_csr = [&](const int* dst, int E, int n, int* rowptr, int* eidx) {
        hipMemsetAsync(cnt, 0, (size_t)n * sizeof(int), stream);
        hist_k<<<gupd((size_t)E), 256, 0, stream>>>(cnt, dst, E);
        scan_k<<<1, 256, 0, stream>>>(rowptr, cnt, n);
        hipMemcpyAsync(cursor, rowptr, (size_t)n * sizeof(int), hipMemcpyDeviceToDevice, stream);
        fill_k<<<gupd((size_t)E), 256, 0, stream>>>(eidx, cursor, dst, E);
    };
    build_csr(vert_dst, Ev, Nv, rp_v, ei_v);
    build_csr(comp_dst, Ec, NG, rp_c, ei_c);
    build_csr(site_dst, Es, Ns, rp_s, ei_s);
    build_csr(masf_dst, Em, Nm, rp_m, ei_m);
    build_csr(prot_dst, Ep, NA, rp_p, ei_p);
    build_csr(prom_dst, Ep, NA, rp_q, ei_q);
    build_csr(anch_dst, Ea, NA, rp_a, ei_a);
    build_csr(vbatch,   Nv, B,  rp_b, ei_b);

    // ---- GRU weight transposes (Wih.T, Whh.T) ----------------------------
    transpose_k<<<gupd((size_t)3 * HD * HD), 256, 0, stream>>>(WTm_ih, gm_Wih, 3 * HD, HD);
    transpose_k<<<gupd((size_t)3 * HD * HD), 256, 0, stream>>>(WTm_hh, gm_Whh, 3 * HD, HD);
    transpose_k<<<gupd((size_t)3 * HD * HD), 256, 0, stream>>>(WTs_ih, gs_Wih, 3 * HD, HD);
    transpose_k<<<gupd((size_t)3 * HD * HD), 256, 0, stream>>>(WTs_hh, gs_Whh, 3 * HD, HD);

    // ---- embedding + super-node init ------------------------------------
    gemm(stream, vert_x, W_emb, b_emb, vert, Nv, FV, HD, 0, 1);
    seg_gather<<<gup4(B), 256, 0, stream>>>(supe, vert, rp_b, ei_b, nullptr, nullptr,
                                            nullptr, B, HD, 0, 0, 0);

    // ---- GWM iterations ---------------------------------------------------
    float* Ta = T;            float* Tb = T + NvH;     float* Tc = T + 2 * NvH;
    float* Td = T + 3 * NvH;  float* Te = T + 4 * NvH; float* Tf = T + 7 * NvH;
    for (int t = 0; t < D; ++t) {
        const float* Wmain = gW_main + (size_t)t * HD * HD;
        const float* Ws2m  = gW_s2m  + (size_t)t * HD * HD;
        const float* Wgm   = gW_gm   + (size_t)t * 2 * HD * HD;
        const float* bgm   = gb_gm   + (size_t)t * HD;
        const float* Wq    = gW_q    + (size_t)t * HD * HD;
        const float* Wk    = gW_k    + (size_t)t * HD * HD;
        const float* Wmrg  = gW_mrg  + (size_t)t * HD * HD;
        const float* Wgs   = gW_gs   + (size_t)t * 2 * HD * HD;
        const float* bgs   = gb_gs   + (size_t)t * HD;

        // h_main = LRELU(seg_sum((vert@Wmain)[src], dst))
        gemm(stream, vert, Wmain, nullptr, Ta, Nv, HD, HD, 0, 0);
        seg_gather<<<gup4((size_t)Nv), 256, 0, stream>>>(Tb, Ta, rp_v, ei_v, vert_src,
                                                         nullptr, nullptr, Nv, HD, 0, 1, 0);
        // trans = LRELU(supe@Ws2m)[batch]
        gemm(stream, supe, Ws2m, nullptr, tsml, B, HD, HD, 0, 1);
        gather128<<<gupd(NvH), 256, 0, stream>>>(Tc, tsml, vbatch, Nv);
        // z = sigmoid([h_main|trans]@Wgm + bgm); x = z*h_main + (1-z)*trans
        gemm(stream, Tb, Wgm, bgm, Td, Nv, HD, HD, 0, 0);
        gemm(stream, Tc, Wgm + (size_t)HD * HD, nullptr, Td, Nv, HD, HD, 1, 2);
        combine_gate<<<gupd(NvH), 256, 0, stream>>>(Td, Tb, Tc, (long)NvH);
        // vert = GRU_main(x, vert)
        gemm(stream, Td, WTm_ih, gm_bih, Te, Nv, HD, 3 * HD, 0, 0);
        gemm(stream, vert, WTm_hh, gm_bhh, Tf, Nv, HD, 3 * HD, 0, 0);
        gru_gate<<<gupd(NvH), 256, 0, stream>>>(vert, Te, Tf, Nv);
        // attention pooling main->super
        gemm(stream, vert, Wk, nullptr, Ta, Nv, HD, HD, 0, 0);
        gemm(stream, supe, Wq, nullptr, qsup, B, HD, HD, 0, 0);
        dot_score<<<gupd((size_t)Nv), 256, 0, stream>>>(score, Ta, qsup, vbatch, Nv);
        hipMemsetAsync(segm, 0, (size_t)B * 4, stream);
        hipMemsetAsync(segd, 0, (size_t)B * 4, stream);
        seg_max_k<<<gupd((size_t)Nv), 256, 0, stream>>>(segm, score, vbatch, Nv);
        seg_expsum_k<<<gupd((size_t)Nv), 256, 0, stream>>>(score, segd, segm, score, vbatch, Nv);
        seg_norm_k<<<gupd((size_t)Nv), 256, 0, stream>>>(score, segd, vbatch, Nv);
        seg_gather<<<gup4(B), 256, 0, stream>>>(pool, vert, rp_b, ei_b, nullptr, score,
                                                nullptr, B, HD, 0, 0, 1);
        // super update
        gemm(stream, pool, Wmrg, nullptr, msup, B, HD, HD, 0, 1);
        gemm(stream, msup, Wgs, bgs, zsup, B, HD, HD, 0, 0);
        gemm(stream, supe, Wgs + (size_t)HD * HD, nullptr, zsup, B, HD, HD, 1, 2);
        combine_gate<<<gupd((size_t)B * HD), 256, 0, stream>>>(zsup, msup, supe, (long)B * HD);
        gemm(stream, zsup, WTs_ih, gs_bih, gis, B, HD, 3 * HD, 0, 0);
        gemm(stream, supe, WTs_hh, gs_bhh, ghs, B, HD, 3 * HD, 0, 0);
        gru_gate<<<gupd((size_t)B * HD), 256, 0, stream>>>(supe, gis, ghs, B);
    }

    // ---- Group module: softmax of zeros == 1/deg -------------------------
    seg_gather<<<gup4((size_t)NG), 256, 0, stream>>>(grp, vert, rp_c, ei_c, comp_src,
                                                     nullptr, nullptr, NG, HD, 0, 0, 2);

    // ---- site conv stack --------------------------------------------------
    float* T1 = T; float* T2 = T + NsH; float* T3 = T + 2 * NsH;
    gemm(stream, site_x, W_s0, nullptr, T1, Ns, Fs, HD, 0, 0);
    seg_gather<<<gup4((size_t)Ns), 256, 0, stream>>>(T2, T1, rp_s, ei_s, site_src,
                                                     nullptr, b_s0, Ns, HD, 0, 1, 0);  // h1
    gemm(stream, T2, W_s1, nullptr, T1, Ns, HD, HD, 0, 0);
    seg_gather<<<gup4((size_t)Ns), 256, 0, stream>>>(T3, T1, rp_s, ei_s, site_src,
                                                     nullptr, b_s1, Ns, HD, 0, 1, 0);  // h2
    gemm(stream, site_x, W_so, b_so, site_o, Ns, Fs, HD, 0, 0);
    gemm(stream, T2, W_so + (size_t)Fs * HD, nullptr, site_o, Ns, HD, HD, 1, 0);
    gemm(stream, T3, W_so + (size_t)(Fs + HD) * HD, nullptr, site_o, Ns, HD, HD, 1, 1);

    // ---- masf conv stack --------------------------------------------------
    gemm(stream, masf_x, W_m0, nullptr, T1, Nm, Fm, HD, 0, 0);
    seg_gather<<<gup4((size_t)Nm), 256, 0, stream>>>(T2, T1, rp_m, ei_m, masf_src,
                                                     nullptr, b_m0, Nm, HD, 0, 1, 0);
    gemm(stream, T2, W_m1, nullptr, T1, Nm, HD, HD, 0, 0);
    seg_gather<<<gup4((size_t)Nm), 256, 0, stream>>>(T3, T1, rp_m, ei_m, masf_src,
                                                     nullptr, b_m1, Nm, HD, 0, 1, 0);
    gemm(stream, masf_x, W_mo, b_mo, masf_o, Nm, Fm, HD, 0, 0);
    gemm(stream, T2, W_mo + (size_t)Fm * HD, nullptr, masf_o, Nm, HD, HD, 1, 0);
    gemm(stream, T3, W_mo + (size_t)(Fm + HD) * HD, nullptr, masf_o, Nm, HD, HD, 1, 1);

    // ---- anchor pooling: in-wave softmax(6-attr) --------------------------
    seg_gather<<<gup4((size_t)NA), 256, 0, stream>>>(anch, site_o, rp_p, ei_p, prot_src,
                                                     prot_ea, nullptr, NA, 2 * HD, 0, 0, 3);
    seg_gather<<<gup4((size_t)NA), 256, 0, stream>>>(anch, masf_o, rp_q, ei_q, prom_src,
                                                     prom_ea, nullptr, NA, 2 * HD, HD, 0, 3);

    // ---- anchor conv stack -------------------------------------------------
    gemm(stream, anch, W_a0, nullptr, axw, NA, 2 * HD, HD, 0, 0);
    seg_gather<<<gup4((size_t)NA), 256, 0, stream>>>(ah1, axw, rp_a, ei_a, anch_src,
                                                     nullptr, b_a0, NA, HD, 0, 1, 0);
    gemm(stream, ah1, W_a1, nullptr, axw, NA, HD, HD, 0, 0);
    seg_gather<<<gup4((size_t)NA), 256, 0, stream>>>(ah2, axw, rp_a, ei_a, anch_src,
                                                     nullptr, b_a1, NA, HD, 0, 1, 0);
    gemm(stream, anch, W_ao, b_ao, aout, NA, 2 * HD, HD, 0, 0);
    gemm(stream, ah1, W_ao + (size_t)2 * HD * HD, nullptr, aout, NA, HD, HD, 1, 0);
    gemm(stream, ah2, W_ao + (size_t)3 * HD * HD, nullptr, aout, NA, HD, HD, 1, 1);

    // ---- distance heads ----------------------------------------------------
    gemm(stream, aout, W_ds, b_ds, pa, NA, HD, HD, 0, 1);
    gemm(stream, grp,  W_dc, b_dc, pg, NG, HD, HD, 0, 1);
    float* outp = (float*)d_out;
    pdist_k<<<gupd((size_t)Pag), 256, 0, stream>>>(outp, pa, pg, ag_a, ag_g, Pag);
    pdist_k<<<gupd((size_t)Paa), 256, 0, stream>>>(outp + Pag, pa, pa, aa0, aa1, Paa);
    pdist_k<<<gupd((size_t)Pgg), 256, 0, stream>>>(outp + Pag + Paa, pg, pg, gg0, gg1, Pgg);
}

// Round 4
// 3371.119 us; speedup vs baseline: 1.1127x; 1.1127x over previous
//
#include <hip/hip_runtime.h>
#include <math.h>

#define HD 128  // hidden dim

// ---------------------------------------------------------------- GEMM
// C[M,N] (+)= A[M,K] @ W[K,N] (+bias), act: 0 none, 1 lrelu, 2 sigmoid
// 256 threads, 128x128 tile, each thread 4 rows x 16 cols, BK=32.
#define BM 128
#define BK 32

__global__ __launch_bounds__(256)
void gemm_kernel(const float* __restrict__ A, const float* __restrict__ W,
                 const float* __restrict__ bias, float* __restrict__ C,
                 int M, int K, int N, int acc, int act)
{
    __shared__ float sA[BM][BK + 1];   // +1 pad: conflict-free per-row reads
    __shared__ float sW[BK][128];

    const int tid = threadIdx.x;
    const int r0 = (tid >> 3) * 4;     // 0..124
    const int c0 = (tid & 7) * 16;     // 0..112
    const int mBase = blockIdx.x * BM;
    const int nBase = blockIdx.y * 128;
    const bool k4 = (K & 3) == 0;

    float accv[4][16];
#pragma unroll
    for (int i = 0; i < 4; ++i)
#pragma unroll
        for (int j = 0; j < 16; ++j) accv[i][j] = 0.f;

    const int kTiles = (K + BK - 1) / BK;
    for (int kt = 0; kt < kTiles; ++kt) {
        const int k0 = kt * BK;
#pragma unroll
        for (int p = 0; p < 4; ++p) {
            int row = p * 32 + (tid >> 3);
            int kq  = (tid & 7) * 4;
            int gr  = mBase + row;
            float v0 = 0.f, v1 = 0.f, v2 = 0.f, v3 = 0.f;
            if (gr < M) {
                const float* ap = A + (size_t)gr * K + k0 + kq;
                if (k4 && k0 + kq + 3 < K) {
                    float4 v = *(const float4*)ap;
                    v0 = v.x; v1 = v.y; v2 = v.z; v3 = v.w;
                } else {
                    if (k0 + kq + 0 < K) v0 = ap[0];
                    if (k0 + kq + 1 < K) v1 = ap[1];
                    if (k0 + kq + 2 < K) v2 = ap[2];
                    if (k0 + kq + 3 < K) v3 = ap[3];
                }
            }
            sA[row][kq + 0] = v0; sA[row][kq + 1] = v1;
            sA[row][kq + 2] = v2; sA[row][kq + 3] = v3;
        }
#pragma unroll
        for (int p = 0; p < 4; ++p) {
            int lin = p * 1024 + tid * 4;
            int kr = lin >> 7, nc = lin & 127;
            float4 v = make_float4(0.f, 0.f, 0.f, 0.f);
            if (k0 + kr < K) v = *(const float4*)(W + (size_t)(k0 + kr) * N + nBase + nc);
            *(float4*)&sW[kr][nc] = v;
        }
        __syncthreads();
#pragma unroll 4
        for (int k = 0; k < BK; ++k) {
            float a0 = sA[r0 + 0][k], a1 = sA[r0 + 1][k];
            float a2 = sA[r0 + 2][k], a3 = sA[r0 + 3][k];
            float wv[16];
            *(float4*)&wv[0]  = *(const float4*)&sW[k][c0 + 0];
            *(float4*)&wv[4]  = *(const float4*)&sW[k][c0 + 4];
            *(float4*)&wv[8]  = *(const float4*)&sW[k][c0 + 8];
            *(float4*)&wv[12] = *(const float4*)&sW[k][c0 + 12];
#pragma unroll
            for (int j = 0; j < 16; ++j) {
                accv[0][j] += a0 * wv[j];
                accv[1][j] += a1 * wv[j];
                accv[2][j] += a2 * wv[j];
                accv[3][j] += a3 * wv[j];
            }
        }
        __syncthreads();
    }

    float bb[16];
    if (bias) {
#pragma unroll
        for (int q = 0; q < 4; ++q)
            *(float4*)&bb[q * 4] = *(const float4*)(bias + nBase + c0 + q * 4);
    } else {
#pragma unroll
        for (int j = 0; j < 16; ++j) bb[j] = 0.f;
    }
#pragma unroll
    for (int i = 0; i < 4; ++i) {
        int gr = mBase + r0 + i;
        if (gr >= M) continue;
        float* cp = C + (size_t)gr * N + nBase + c0;
#pragma unroll
        for (int q = 0; q < 4; ++q) {
            float4 old;
            if (acc) old = *(const float4*)(cp + q * 4);
            float o[4];
#pragma unroll
            for (int u = 0; u < 4; ++u) {
                float v = accv[i][q * 4 + u] + bb[q * 4 + u];
                if (acc) v += ((const float*)&old)[u];
                if (act == 1) v = v > 0.f ? v : 0.1f * v;
                else if (act == 2) v = 1.f / (1.f + expf(-v));
                o[u] = v;
            }
            *(float4*)(cp + q * 4) = make_float4(o[0], o[1], o[2], o[3]);
        }
    }
}

// ---------------------------------------------------------------- CSR build
__global__ void hist_k(int* __restrict__ cnt, const int* __restrict__ dst, int E)
{
    int i = blockIdx.x * 256 + threadIdx.x;
    if (i < E) atomicAdd(&cnt[dst[i]], 1);
}

// ---- global 3-phase exclusive scan over concatenated counts -------------
#define SCB 4096  // elements per block = 256 threads x 16

__global__ __launch_bounds__(256)
void scan_sums(const int* __restrict__ cnt, int n, int* __restrict__ bsum)
{
    __shared__ int red[256];
    int t = threadIdx.x;
    int base = blockIdx.x * SCB + t * 16;
    int s = 0;
#pragma unroll
    for (int i = 0; i < 16; ++i) { int idx = base + i; if (idx < n) s += cnt[idx]; }
    red[t] = s; __syncthreads();
    for (int st = 128; st > 0; st >>= 1) {
        if (t < st) red[t] += red[t + st];
        __syncthreads();
    }
    if (t == 0) bsum[blockIdx.x] = red[0];
}

__global__ void scan_bsum(int* __restrict__ bsum, int nb)
{
    if (threadIdx.x == 0) {
        int run = 0;
        for (int i = 0; i < nb; ++i) { int v = bsum[i]; bsum[i] = run; run += v; }
    }
}

__global__ __launch_bounds__(256)
void scan_write(const int* __restrict__ cnt, int n, const int* __restrict__ bsum,
                int* __restrict__ rp)
{
    __shared__ int a0[256], a1[256];
    int t = threadIdx.x;
    int base = blockIdx.x * SCB + t * 16;
    int v[16]; int s = 0;
#pragma unroll
    for (int i = 0; i < 16; ++i) { int idx = base + i; v[i] = (idx < n) ? cnt[idx] : 0; s += v[i]; }
    a0[t] = s; __syncthreads();
    int* cur = a0; int* nxt = a1;
    for (int st = 1; st < 256; st <<= 1) {
        int val = cur[t] + ((t >= st) ? cur[t - st] : 0);
        nxt[t] = val; __syncthreads();
        int* tmp = cur; cur = nxt; nxt = tmp;
    }
    int run = bsum[blockIdx.x] + (t > 0 ? cur[t - 1] : 0);
#pragma unroll
    for (int i = 0; i < 16; ++i) {
        int idx = base + i;
        if (idx < n) {
            rp[idx] = run; run += v[i];
            if (idx == n - 1) rp[n] = run;
        }
    }
}

__global__ void fill_k(int* __restrict__ eidx, int* __restrict__ cursor,
                       const int* __restrict__ dst, int E)
{
    int i = blockIdx.x * 256 + threadIdx.x;
    if (i < E) eidx[atomicAdd(&cursor[dst[i]], 1)] = i;
}

// ---------------------------------------------------------------- CSR gather
// One wave (64 lanes) per destination row; lane covers 2 feats (float2).
// out[d*ostride+ooff+:] = act( bias + sum_e w_e * X[src[e]][:] )
// mode 0: w=1   1: w=wattr[e]   2: w=1/deg   3: w=softmax(6-wattr)[e]
__global__ __launch_bounds__(256)
void seg_gather(float* __restrict__ out, const float* __restrict__ X,
                const int* __restrict__ rowptr, const int* __restrict__ eidx,
                const int* __restrict__ src, const float* __restrict__ wattr,
                const float* __restrict__ bias, int n, int ostride, int ooff,
                int act, int mode)
{
    int d = blockIdx.x * 4 + (threadIdx.x >> 6);
    if (d >= n) return;
    int lane = threadIdx.x & 63;
    int lo = rowptr[d], hi = rowptr[d + 1];
    float w0 = 1.f, mx = 0.f, iden = 0.f;
    if (mode == 2) w0 = (hi > lo) ? 1.f / (float)(hi - lo) : 0.f;
    if (mode == 3) {
        mx = -1e30f;
        for (int i = lo; i < hi; ++i) mx = fmaxf(mx, 6.f - wattr[eidx[i]]);
        float den = 0.f;
        for (int i = lo; i < hi; ++i) den += expf(6.f - wattr[eidx[i]] - mx);
        iden = 1.f / den;
    }
    float ax = 0.f, ay = 0.f;
    for (int i = lo; i < hi; ++i) {
        int e = eidx[i];
        int s = src ? src[e] : e;
        float w;
        if (mode == 0) w = 1.f;
        else if (mode == 1) w = wattr[e];
        else if (mode == 2) w = w0;
        else w = expf(6.f - wattr[e] - mx) * iden;
        float2 v = *(const float2*)(X + (size_t)s * HD + 2 * lane);
        ax += w * v.x; ay += w * v.y;
    }
    if (bias) { float2 b = *(const float2*)(bias + 2 * lane); ax += b.x; ay += b.y; }
    if (act == 1) { ax = ax > 0.f ? ax : 0.1f * ax; ay = ay > 0.f ? ay : 0.1f * ay; }
    *(float2*)(out + (size_t)d * ostride + ooff + 2 * lane) = make_float2(ax, ay);
}

// ---------------------------------------------------------------- misc kernels
__global__ void gather128(float* __restrict__ out, const float* __restrict__ in,
                          const int* __restrict__ idx, int n)
{
    long i = (long)blockIdx.x * 256 + threadIdx.x;
    if (i >= (long)n * HD) return;
    int r = (int)(i >> 7), f = (int)(i & 127);
    out[i] = in[(size_t)idx[r] * HD + f];
}

// in-place: z -> z*h + (1-z)*t
__global__ void combine_gate(float* __restrict__ zx, const float* __restrict__ h,
                             const float* __restrict__ t, long n)
{
    long i = (long)blockIdx.x * 256 + threadIdx.x;
    if (i >= n) return;
    float z = zx[i];
    zx[i] = z * h[i] + (1.f - z) * t[i];
}

// torch GRUCell gate math; h [M,128] in place, gi/gh [M,384] (bias already added)
__global__ void gru_gate(float* __restrict__ h, const float* __restrict__ gi,
                         const float* __restrict__ gh, int M)
{
    long i = (long)blockIdx.x * 256 + threadIdx.x;
    if (i >= (long)M * HD) return;
    int row = (int)(i >> 7), f = (int)(i & 127);
    size_t o = (size_t)row * 384 + f;
    float r = 1.f / (1.f + expf(-(gi[o] + gh[o])));
    float z = 1.f / (1.f + expf(-(gi[o + 128] + gh[o + 128])));
    float n = tanhf(gi[o + 256] + r * gh[o + 256]);
    h[i] = (1.f - z) * n + z * h[i];
}

__global__ void transpose_k(float* __restrict__ out, const float* __restrict__ in, int R, int C)
{
    long i = (long)blockIdx.x * 256 + threadIdx.x;
    if (i >= (long)R * C) return;
    int r = (int)(i / C), c = (int)(i % C);
    out[(size_t)c * R + r] = in[i];
}

__global__ void dot_score(float* __restrict__ sc, const float* __restrict__ kb,
                          const float* __restrict__ qs, const int* __restrict__ batch, int n)
{
    int v = blockIdx.x * 256 + threadIdx.x;
    if (v >= n) return;
    const float4* a = (const float4*)(kb + (size_t)v * HD);
    const float4* q = (const float4*)(qs + (size_t)batch[v] * HD);
    float acc = 0.f;
#pragma unroll
    for (int i = 0; i < 32; ++i) {
        float4 x = a[i], y = q[i];
        acc += x.x * y.x + x.y * y.y + x.z * y.z + x.w * y.w;
    }
    sc[v] = acc * 0.08838834764831843f;  // 1/sqrt(128)
}

// order-preserving float<->uint for atomicMax (memset-0 init == -inf)
__device__ __forceinline__ unsigned enc_f(float f) {
    unsigned u = __float_as_uint(f);
    return (u & 0x80000000u) ? ~u : (u | 0x80000000u);
}
__device__ __forceinline__ float dec_f(unsigned u) {
    return (u & 0x80000000u) ? __uint_as_float(u & 0x7fffffffu) : __uint_as_float(~u);
}

__global__ void seg_max_k(unsigned* __restrict__ m, const float* __restrict__ s,
                          const int* __restrict__ seg, int n)
{
    int i = blockIdx.x * 256 + threadIdx.x;
    if (i < n) atomicMax(&m[seg[i]], enc_f(s[i]));
}
__global__ void seg_expsum_k(float* __restrict__ ev, float* __restrict__ d,
                             const unsigned* __restrict__ m, const float* __restrict__ s,
                             const int* __restrict__ seg, int n)
{
    int i = blockIdx.x * 256 + threadIdx.x;
    if (i >= n) return;
    float e = expf(s[i] - dec_f(m[seg[i]]));
    ev[i] = e;
    atomicAdd(&d[seg[i]], e);
}
__global__ void seg_norm_k(float* __restrict__ wv, const float* __restrict__ d,
                           const int* __restrict__ seg, int n)
{
    int i = blockIdx.x * 256 + threadIdx.x;
    if (i < n) wv[i] /= d[seg[i]];
}

__global__ void pdist_k(float* __restrict__ out, const float* __restrict__ A,
                        const float* __restrict__ Bm, const int* __restrict__ ia,
                        const int* __restrict__ ib, int P)
{
    int p = blockIdx.x * 256 + threadIdx.x;
    if (p >= P) return;
    const float4* a = (const float4*)(A + (size_t)ia[p] * HD);
    const float4* b = (const float4*)(Bm + (size_t)ib[p] * HD);
    float acc = 0.f;
#pragma unroll
    for (int i = 0; i < 32; ++i) {
        float4 x = a[i], y = b[i];
        float d0 = x.x - y.x + 1e-6f, d1 = x.y - y.y + 1e-6f;
        float d2 = x.z - y.z + 1e-6f, d3 = x.w - y.w + 1e-6f;
        acc += d0 * d0 + d1 * d1 + d2 * d2 + d3 * d3;
    }
    out[p] = sqrtf(acc);
}

// ---------------------------------------------------------------- host

static inline unsigned gupd(size_t n) { return (unsigned)((n + 255) / 256); }
static inline unsigned gup4(size_t n) { return (unsigned)((n + 3) / 4); }

static void gemm(hipStream_t st, const float* A, const float* W, const float* bias,
                 float* C, int M, int K, int N, int acc, int act)
{
    dim3 g((M + BM - 1) / BM, N / 128);
    hipLaunchKernelGGL(gemm_kernel, g, dim3(256), 0, st, A, W, bias, C, M, K, N, acc, act);
}

extern "C" void kernel_launch(void* const* d_in, const int* in_sizes, int n_in,
                              void* d_out, int out_size, void* d_ws, size_t ws_size,
                              hipStream_t stream)
{
    (void)n_in; (void)out_size;
    const float* vert_x  = (const float*)d_in[0];
    const float* site_x  = (const float*)d_in[1];
    const float* masf_x  = (const float*)d_in[2];
    const float* prot_ea = (const float*)d_in[3];
    const float* prom_ea = (const float*)d_in[4];
    const int* vert_src = (const int*)d_in[5];
    const int* vert_dst = (const int*)d_in[6];
    const int* vbatch   = (const int*)d_in[7];
    const int* comp_src = (const int*)d_in[8];
    const int* comp_dst = (const int*)d_in[9];
    const int* site_src = (const int*)d_in[10];
    const int* site_dst = (const int*)d_in[11];
    const int* masf_src = (const int*)d_in[12];
    const int* masf_dst = (const int*)d_in[13];
    const int* prot_src = (const int*)d_in[14];
    const int* prot_dst = (const int*)d_in[15];
    const int* prom_src = (const int*)d_in[16];
    const int* prom_dst = (const int*)d_in[17];
    const int* anch_src = (const int*)d_in[18];
    const int* anch_dst = (const int*)d_in[19];
    const int* ag_a = (const int*)d_in[20];
    const int* ag_g = (const int*)d_in[21];
    const int* aa0  = (const int*)d_in[22];
    const int* aa1  = (const int*)d_in[23];
    const int* gg0  = (const int*)d_in[24];
    const int* gg1  = (const int*)d_in[25];
    const float* W_emb = (const float*)d_in[26];
    const float* b_emb = (const float*)d_in[27];
    const float* gW_main = (const float*)d_in[28];
    const float* gW_s2m  = (const float*)d_in[29];
    const float* gW_gm   = (const float*)d_in[30];
    const float* gb_gm   = (const float*)d_in[31];
    const float* gW_q    = (const float*)d_in[32];
    const float* gW_k    = (const float*)d_in[33];
    const float* gW_mrg  = (const float*)d_in[34];
    const float* gW_gs   = (const float*)d_in[35];
    const float* gb_gs   = (const float*)d_in[36];
    const float* gm_Wih = (const float*)d_in[37];
    const float* gm_Whh = (const float*)d_in[38];
    const float* gm_bih = (const float*)d_in[39];
    const float* gm_bhh = (const float*)d_in[40];
    const float* gs_Wih = (const float*)d_in[41];
    const float* gs_Whh = (const float*)d_in[42];
    const float* gs_bih = (const float*)d_in[43];
    const float* gs_bhh = (const float*)d_in[44];
    const float* W_s0 = (const float*)d_in[45];
    const float* b_s0 = (const float*)d_in[46];
    const float* W_s1 = (const float*)d_in[47];
    const float* b_s1 = (const float*)d_in[48];
    const float* W_so = (const float*)d_in[49];
    const float* b_so = (const float*)d_in[50];
    const float* W_m0 = (const float*)d_in[51];
    const float* b_m0 = (const float*)d_in[52];
    const float* W_m1 = (const float*)d_in[53];
    const float* b_m1 = (const float*)d_in[54];
    const float* W_mo = (const float*)d_in[55];
    const float* b_mo = (const float*)d_in[56];
    const float* W_a0 = (const float*)d_in[57];
    const float* b_a0 = (const float*)d_in[58];
    const float* W_a1 = (const float*)d_in[59];
    const float* b_a1 = (const float*)d_in[60];
    const float* W_ao = (const float*)d_in[61];
    const float* b_ao = (const float*)d_in[62];
    const float* W_ds = (const float*)d_in[63];
    const float* b_ds = (const float*)d_in[64];
    const float* W_dc = (const float*)d_in[65];
    const float* b_dc = (const float*)d_in[66];

    const int B = 256, NG = 4000, NA = 10000, Ns = 80000, Nm = 80000;
    const int Nv = in_sizes[7];
    const int FV = in_sizes[0] / Nv;
    const int Fs = in_sizes[1] / Ns;
    const int Fm = in_sizes[2] / Nm;
    const int Ev = in_sizes[5], Ec = in_sizes[8], Es = in_sizes[10], Em = in_sizes[12];
    const int Ep = in_sizes[14], Ea = in_sizes[18];
    const int Pag = in_sizes[20], Paa = in_sizes[22], Pgg = in_sizes[24];
    const int D = in_sizes[28] / (HD * HD);

    // ---- workspace layout (floats) --------------------------------------
    float* ws = (float*)d_ws;
    size_t off = 0;
    auto take = [&](size_t n) { size_t o = off; off += n; return o; };
    float* vert  = ws + take((size_t)Nv * HD);
    float* supe  = ws + take((size_t)B * HD);
    float* qsup  = ws + take((size_t)B * HD);
    float* pool  = ws + take((size_t)B * HD);
    float* msup  = ws + take((size_t)B * HD);
    float* zsup  = ws + take((size_t)B * HD);
    float* gis   = ws + take((size_t)B * 3 * HD);
    float* ghs   = ws + take((size_t)B * 3 * HD);
    float* tsml  = ws + take((size_t)B * HD);
    float* grp   = ws + take((size_t)NG * HD);
    float* site_o = ws + take((size_t)Ns * HD);
    float* masf_o = ws + take((size_t)Nm * HD);
    float* anch  = ws + take((size_t)NA * 2 * HD);
    float* ah1   = ws + take((size_t)NA * HD);
    float* ah2   = ws + take((size_t)NA * HD);
    float* axw   = ws + take((size_t)NA * HD);
    float* aout  = ws + take((size_t)NA * HD);
    float* pa    = ws + take((size_t)NA * HD);
    float* pg    = ws + take((size_t)NG * HD);
    float* score = ws + take((size_t)Nv);
    unsigned* segm = (unsigned*)(ws + take((size_t)B));
    float* segd  = ws + take((size_t)B);
    float* WTm_ih = ws + take((size_t)3 * HD * HD);
    float* WTm_hh = ws + take((size_t)3 * HD * HD);
    float* WTs_ih = ws + take((size_t)3 * HD * HD);
    float* WTs_hh = ws + take((size_t)3 * HD * HD);
    const size_t NvH = (size_t)Nv * HD, NsH = (size_t)Ns * HD;
    float* T = ws + take(3 * NsH);   // shared temp region

    // ---- CSR arrays (ints), concatenated layout --------------------------
    // graph order: v(Nv,Ev) c(NG,Ec) s(Ns,Es) m(Nm,Em) p(NA,Ep) q(NA,Ep) a(NA,Ea) b(B,Nv)
    const int nN[8] = {Nv, NG, Ns, Nm, NA, NA, NA, B};
    const int nE[8] = {Ev, Ec, Es, Em, Ep, Ep, Ea, Nv};
    const int* dsts[8] = {vert_dst, comp_dst, site_dst, masf_dst,
                          prot_dst, prom_dst, anch_dst, vbatch};
    int baseN[9], baseE[9];
    baseN[0] = 0; baseE[0] = 0;
    for (int g = 0; g < 8; ++g) { baseN[g + 1] = baseN[g] + nN[g]; baseE[g + 1] = baseE[g] + nE[g]; }
    const int totN = baseN[8], totE = baseE[8];

    int* ib = (int*)(ws + off);
    size_t ioff = 0;
    auto taki = [&](size_t n) { size_t o = ioff; ioff += n; return o; };
    int* cnt_all = ib + taki((size_t)totN);
    int* rp_all  = ib + taki((size_t)totN + 1);
    int* cur_all = ib + taki((size_t)totN);
    int* ei_all  = ib + taki((size_t)totE);
    int* bsum    = ib + taki((size_t)((totN + SCB - 1) / SCB) + 1);
    if (ws_size < off * sizeof(float) + ioff * sizeof(int)) return;

    // histogram all graphs into concatenated counts
    hipMemsetAsync(cnt_all, 0, (size_t)totN * sizeof(int), stream);
    for (int g = 0; g < 8; ++g)
        hist_k<<<gupd((size_t)nE[g]), 256, 0, stream>>>(cnt_all + baseN[g], dsts[g], nE[g]);
    // global 3-phase exclusive scan -> rp_all (values index into ei_all pool)
    const int nScanBlocks = (totN + SCB - 1) / SCB;
    scan_sums<<<nScanBlocks, 256, 0, stream>>>(cnt_all, totN, bsum);
    scan_bsum<<<1, 64, 0, stream>>>(bsum, nScanBlocks);
    scan_write<<<nScanBlocks, 256, 0, stream>>>(cnt_all, totN, bsum, rp_all);
    // fill edge indices
    hipMemcpyAsync(cur_all, rp_all, (size_t)totN * sizeof(int), hipMemcpyDeviceToDevice, stream);
    for (int g = 0; g < 8; ++g)
        fill_k<<<gupd((size_t)nE[g]), 256, 0, stream>>>(ei_all, cur_all + baseN[g], dsts[g], nE[g]);

    const int* rp_v = rp_all + baseN[0];
    const int* rp_c = rp_all + baseN[1];
    const int* rp_s = rp_all + baseN[2];
    const int* rp_m = rp_all + baseN[3];
    const int* rp_p = rp_all + baseN[4];
    const int* rp_q = rp_all + baseN[5];
    const int* rp_a = rp_all + baseN[6];
    const int* rp_b = rp_all + baseN[7];
    const int* ei = ei_all;  // rowptr values are global into the single pool

    // ---- GRU weight transposes (Wih.T, Whh.T) ----------------------------
    transpose_k<<<gupd((size_t)3 * HD * HD), 256, 0, stream>>>(WTm_ih, gm_Wih, 3 * HD, HD);
    transpose_k<<<gupd((size_t)3 * HD * HD), 256, 0, stream>>>(WTm_hh, gm_Whh, 3 * HD, HD);
    transpose_k<<<gupd((size_t)3 * HD * HD), 256, 0, stream>>>(WTs_ih, gs_Wih, 3 * HD, HD);
    transpose_k<<<gupd((size_t)3 * HD * HD), 256, 0, stream>>>(WTs_hh, gs_Whh, 3 * HD, HD);

    // ---- embedding + super-node init ------------------------------------
    gemm(stream, vert_x, W_emb, b_emb, vert, Nv, FV, HD, 0, 1);
    seg_gather<<<gup4(B), 256, 0, stream>>>(supe, vert, rp_b, ei, nullptr, nullptr,
                                            nullptr, B, HD, 0, 0, 0);

    // ---- GWM iterations ---------------------------------------------------
    float* Ta = T;            float* Tb = T + NvH;     float* Tc = T + 2 * NvH;
    float* Td = T + 3 * NvH;  float* Te = T + 4 * NvH; float* Tf = T + 7 * NvH;
    for (int t = 0; t < D; ++t) {
        const float* Wmain = gW_main + (size_t)t * HD * HD;
        const float* Ws2m  = gW_s2m  + (size_t)t * HD * HD;
        const float* Wgm   = gW_gm   + (size_t)t * 2 * HD * HD;
        const float* bgm   = gb_gm   + (size_t)t * HD;
        const float* Wq    = gW_q    + (size_t)t * HD * HD;
        const float* Wk    = gW_k    + (size_t)t * HD * HD;
        const float* Wmrg  = gW_mrg  + (size_t)t * HD * HD;
        const float* Wgs   = gW_gs   + (size_t)t * 2 * HD * HD;
        const float* bgs   = gb_gs   + (size_t)t * HD;

        // h_main = LRELU(seg_sum((vert@Wmain)[src], dst))
        gemm(stream, vert, Wmain, nullptr, Ta, Nv, HD, HD, 0, 0);
        seg_gather<<<gup4((size_t)Nv), 256, 0, stream>>>(Tb, Ta, rp_v, ei, vert_src,
                                                         nullptr, nullptr, Nv, HD, 0, 1, 0);
        // trans = LRELU(supe@Ws2m)[batch]
        gemm(stream, supe, Ws2m, nullptr, tsml, B, HD, HD, 0, 1);
        gather128<<<gupd(NvH), 256, 0, stream>>>(Tc, tsml, vbatch, Nv);
        // z = sigmoid([h_main|trans]@Wgm + bgm); x = z*h_main + (1-z)*trans
        gemm(stream, Tb, Wgm, bgm, Td, Nv, HD, HD, 0, 0);
        gemm(stream, Tc, Wgm + (size_t)HD * HD, nullptr, Td, Nv, HD, HD, 1, 2);
        combine_gate<<<gupd(NvH), 256, 0, stream>>>(Td, Tb, Tc, (long)NvH);
        // vert = GRU_main(x, vert)
        gemm(stream, Td, WTm_ih, gm_bih, Te, Nv, HD, 3 * HD, 0, 0);
        gemm(stream, vert, WTm_hh, gm_bhh, Tf, Nv, HD, 3 * HD, 0, 0);
        gru_gate<<<gupd(NvH), 256, 0, stream>>>(vert, Te, Tf, Nv);
        // attention pooling main->super
        gemm(stream, vert, Wk, nullptr, Ta, Nv, HD, HD, 0, 0);
        gemm(stream, supe, Wq, nullptr, qsup, B, HD, HD, 0, 0);
        dot_score<<<gupd((size_t)Nv), 256, 0, stream>>>(score, Ta, qsup, vbatch, Nv);
        hipMemsetAsync(segm, 0, (size_t)B * 4, stream);
        hipMemsetAsync(segd, 0, (size_t)B * 4, stream);
        seg_max_k<<<gupd((size_t)Nv), 256, 0, stream>>>(segm, score, vbatch, Nv);
        seg_expsum_k<<<gupd((size_t)Nv), 256, 0, stream>>>(score, segd, segm, score, vbatch, Nv);
        seg_norm_k<<<gupd((size_t)Nv), 256, 0, stream>>>(score, segd, vbatch, Nv);
        seg_gather<<<gup4(B), 256, 0, stream>>>(pool, vert, rp_b, ei, nullptr, score,
                                                nullptr, B, HD, 0, 0, 1);
        // super update
        gemm(stream, pool, Wmrg, nullptr, msup, B, HD, HD, 0, 1);
        gemm(stream, msup, Wgs, bgs, zsup, B, HD, HD, 0, 0);
        gemm(stream, supe, Wgs + (size_t)HD * HD, nullptr, zsup, B, HD, HD, 1, 2);
        combine_gate<<<gupd((size_t)B * HD), 256, 0, stream>>>(zsup, msup, supe, (long)B * HD);
        gemm(stream, zsup, WTs_ih, gs_bih, gis, B, HD, 3 * HD, 0, 0);
        gemm(stream, supe, WTs_hh, gs_bhh, ghs, B, HD, 3 * HD, 0, 0);
        gru_gate<<<gupd((size_t)B * HD), 256, 0, stream>>>(supe, gis, ghs, B);
    }

    // ---- Group module: softmax of zeros == 1/deg -------------------------
    seg_gather<<<gup4((size_t)NG), 256, 0, stream>>>(grp, vert, rp_c, ei, comp_src,
                                                     nullptr, nullptr, NG, HD, 0, 0, 2);

    // ---- site conv stack --------------------------------------------------
    float* T1 = T; float* T2 = T + NsH; float* T3 = T + 2 * NsH;
    gemm(stream, site_x, W_s0, nullptr, T1, Ns, Fs, HD, 0, 0);
    seg_gather<<<gup4((size_t)Ns), 256, 0, stream>>>(T2, T1, rp_s, ei, site_src,
                                                     nullptr, b_s0, Ns, HD, 0, 1, 0);  // h1
    gemm(stream, T2, W_s1, nullptr, T1, Ns, HD, HD, 0, 0);
    seg_gather<<<gup4((size_t)Ns), 256, 0, stream>>>(T3, T1, rp_s, ei, site_src,
                                                     nullptr, b_s1, Ns, HD, 0, 1, 0);  // h2
    gemm(stream, site_x, W_so, b_so, site_o, Ns, Fs, HD, 0, 0);
    gemm(stream, T2, W_so + (size_t)Fs * HD, nullptr, site_o, Ns, HD, HD, 1, 0);
    gemm(stream, T3, W_so + (size_t)(Fs + HD) * HD, nullptr, site_o, Ns, HD, HD, 1, 1);

    // ---- masf conv stack --------------------------------------------------
    gemm(stream, masf_x, W_m0, nullptr, T1, Nm, Fm, HD, 0, 0);
    seg_gather<<<gup4((size_t)Nm), 256, 0, stream>>>(T2, T1, rp_m, ei, masf_src,
                                                     nullptr, b_m0, Nm, HD, 0, 1, 0);
    gemm(stream, T2, W_m1, nullptr, T1, Nm, HD, HD, 0, 0);
    seg_gather<<<gup4((size_t)Nm), 256, 0, stream>>>(T3, T1, rp_m, ei, masf_src,
                                                     nullptr, b_m1, Nm, HD, 0, 1, 0);
    gemm(stream, masf_x, W_mo, b_mo, masf_o, Nm, Fm, HD, 0, 0);
    gemm(stream, T2, W_mo + (size_t)Fm * HD, nullptr, masf_o, Nm, HD, HD, 1, 0);
    gemm(stream, T3, W_mo + (size_t)(Fm + HD) * HD, nullptr, masf_o, Nm, HD, HD, 1, 1);

    // ---- anchor pooling: in-wave softmax(6-attr) --------------------------
    seg_gather<<<gup4((size_t)NA), 256, 0, stream>>>(anch, site_o, rp_p, ei, prot_src,
                                                     prot_ea, nullptr, NA, 2 * HD, 0, 0, 3);
    seg_gather<<<gup4((size_t)NA), 256, 0, stream>>>(anch, masf_o, rp_q, ei, prom_src,
                                                     prom_ea, nullptr, NA, 2 * HD, HD, 0, 3);

    // ---- anchor conv stack -------------------------------------------------
    gemm(stream, anch, W_a0, nullptr, axw, NA, 2 * HD, HD, 0, 0);
    seg_gather<<<gup4((size_t)NA), 256, 0, stream>>>(ah1, axw, rp_a, ei, anch_src,
                                                     nullptr, b_a0, NA, HD, 0, 1, 0);
    gemm(stream, ah1, W_a1, nullptr, axw, NA, HD, HD, 0, 0);
    seg_gather<<<gup4((size_t)NA), 256, 0, stream>>>(ah2, axw, rp_a, ei, anch_src,
                                                     nullptr, b_a1, NA, HD, 0, 1, 0);
    gemm(stream, anch, W_ao, b_ao, aout, NA, 2 * HD, HD, 0, 0);
    gemm(stream, ah1, W_ao + (size_t)2 * HD * HD, nullptr, aout, NA, HD, HD, 1, 0);
    gemm(stream, ah2, W_ao + (size_t)3 * HD * HD, nullptr, aout, NA, HD, HD, 1, 1);

    // ---- distance heads ----------------------------------------------------
    gemm(stream, aout, W_ds, b_ds, pa, NA, HD, HD, 0, 1);
    gemm(stream, grp,  W_dc, b_dc, pg, NG, HD, HD, 0, 1);
    float* outp = (float*)d_out;
    pdist_k<<<gupd((size_t)Pag), 256, 0, stream>>>(outp, pa, pg, ag_a, ag_g, Pag);
    pdist_k<<<gupd((size_t)Paa), 256, 0, stream>>>(outp + Pag, pa, pa, aa0, aa1, Paa);
    pdist_k<<<gupd((size_t)Pgg), 256, 0, stream>>>(outp + Pag + Paa, pg, pg, gg0, gg1, Pgg);
}